// Round 6
// baseline (288.835 us; speedup 1.0000x reference)
//
#include <hip/hip_runtime.h>
#include <hip/hip_bf16.h>

// Problem constants (T, B, H, D_MODEL) = (4096, 16, 256, 256)
#define T_LEN 4096
#define BATCH 16
#define NH    256
#define DM    256
#define M_TOT (T_LEN * BATCH)   // 65536 rows for both GEMMs

typedef __hip_bfloat16 bf16;
typedef __attribute__((ext_vector_type(8))) short bf16x8;  // 8 bf16 = 4 VGPRs
typedef __attribute__((ext_vector_type(4))) float f32x4;

// manual RTNE f32->bf16 (bit-level)
__device__ __forceinline__ unsigned short f2bf_bits(float f) {
    unsigned int u = __float_as_uint(f);
    return (unsigned short)((u + 0x7fffu + ((u >> 16) & 1u)) >> 16);
}

__device__ __forceinline__ bf16x8 cvt8(float4 a, float4 b) {
    union { unsigned short s[8]; bf16x8 v; } u;
    u.s[0] = f2bf_bits(a.x); u.s[1] = f2bf_bits(a.y);
    u.s[2] = f2bf_bits(a.z); u.s[3] = f2bf_bits(a.w);
    u.s[4] = f2bf_bits(b.x); u.s[5] = f2bf_bits(b.y);
    u.s[6] = f2bf_bits(b.z); u.s[7] = f2bf_bits(b.w);
    return u.v;
}

// async global->LDS, 16 B per lane. LDS dest must be wave-uniform base;
// HW scatters lane i to base + i*16 (m97/m104 contract -> no LDS padding).
typedef const unsigned int __attribute__((address_space(1)))* gas_ptr;
typedef unsigned int __attribute__((address_space(3)))* las_ptr;
__device__ __forceinline__ void async16(const bf16* g, bf16* l) {
    __builtin_amdgcn_global_load_lds((gas_ptr)g, (las_ptr)l, 16, 0, 0);
}

// ---------------------------------------------------------------------------
// Prep lam: Lam = exp(-exp(nu_log) + i*exp(theta_log)), [2*NH]: re then im.
// ---------------------------------------------------------------------------
__global__ __launch_bounds__(256) void prep_lam_kernel(
    const float* __restrict__ nu_log, const float* __restrict__ theta_log,
    float* __restrict__ lam)
{
    int h = threadIdx.x;
    float mod = expf(-expf(nu_log[h]));   // |Lam| in [e^-e, e^-1]
    float ang = expf(theta_log[h]);
    lam[h]      = mod * cosf(ang);
    lam[NH + h] = mod * sinf(ang);
}

// ---------------------------------------------------------------------------
// Prep weights (bf16, transposed, complex-interleaved). gamma inlined.
// WaT: (512 x 256) [n][k].  n=2h: B_re[h][k]*gam[h]; n=2h+1: B_im[h][k]*gam[h]
// WcT: (256 x 512) [d][k].  k=2h: C_re[d][h];        k=2h+1: -C_im[d][h]
// ---------------------------------------------------------------------------
__global__ __launch_bounds__(256) void prep_w_kernel(
    const float* __restrict__ nu_log,
    const float* __restrict__ B_re, const float* __restrict__ B_im,
    const float* __restrict__ C_re, const float* __restrict__ C_im,
    bf16* __restrict__ WaT, bf16* __restrict__ WcT)
{
    int idx = blockIdx.x * 256 + threadIdx.x;   // covers 2 * 131072
    if (idx < 512 * 256) {
        int n = idx >> 8, k = idx & 255;
        int h = n >> 1;
        float mod = expf(-expf(nu_log[h]));
        float gam = sqrtf(fmaxf(1.0f - mod * mod, 1e-8f));
        float v = ((n & 1) == 0 ? B_re[h * DM + k] : B_im[h * DM + k]) * gam;
        WaT[idx] = __float2bfloat16(v);
    } else {
        int j = idx - 512 * 256;
        int d = j >> 9, k = j & 511;
        int h = k >> 1;
        float v = ((k & 1) == 0) ? C_re[d * NH + h] : -C_im[d * NH + h];
        WcT[j] = __float2bfloat16(v);
    }
}

// ---------------------------------------------------------------------------
// Stage A GEMM: Bu[m][n] = sum_k x[m][k]*WaT[n][k].
// 128x128 tile, BK=32, 8 K-iters. A read DIRECTLY from global f32 (dwordx4 +
// inline cvt to bf16 fragments -- no cvt kernel, no LDS for A). B staged via
// async16 into double-buffered LDS: one barrier per iter, staging overlaps
// MFMA. XCD swizzle: the 4 n-tiles of one m-tile land on one XCD.
// ---------------------------------------------------------------------------
__global__ __launch_bounds__(256) void gemm_a_kernel(
    const float* __restrict__ x,   // (M,256) f32
    const bf16* __restrict__ BT,   // WaT (512,256)
    bf16* __restrict__ Cb)         // Bu (M,512)
{
    __shared__ bf16 sB[2 * 128 * 32];   // 16 KB double-buffered

    const int tid  = threadIdx.x;
    const int lane = tid & 63;
    const int wid  = tid >> 6;

    const int bid = blockIdx.x;          // 2048 blocks
    const int xcd = bid & 7;
    const int sl  = bid >> 3;
    const int nt  = sl & 3;              // 4 n-tiles
    const int mt  = xcd * 64 + (sl >> 2);
    const int m0  = mt * 128;
    const int n0  = nt * 128;

    const int tm  = (wid >> 1) * 64;
    const int tn  = (wid & 1) * 64;
    const int l15 = lane & 15;
    const int q   = lane >> 4;

    // B staging: wave wid covers rows [wid*32, wid*32+32) in 2 issues
    const bf16* gB0 = BT + (size_t)(n0 + wid * 32 + (lane >> 2)) * 256 + (lane & 3) * 8;
    const size_t rstep = (size_t)16 * 256;
    // A fragment base (global, f32): row = m0+tm+i*16+l15, col = k0 + q*8
    const float* gA = x + (size_t)(m0 + tm + l15) * 256 + q * 8;

    f32x4 acc[4][4];
    #pragma unroll
    for (int i = 0; i < 4; ++i)
        #pragma unroll
        for (int j = 0; j < 4; ++j) acc[i][j] = (f32x4){0.f, 0.f, 0.f, 0.f};

    // pre-issue slab 0 into buf 0
    {
        bf16* l = sB + wid * 32 * 32;
        async16(gB0, l);
        async16(gB0 + rstep, l + 16 * 32);
    }

    for (int p = 0; p < 8; ++p) {
        __syncthreads();   // drains slab p (+ previous reads)
        if (p < 7) {       // issue slab p+1 into other buffer; flies during MFMA
            const bf16* g = gB0 + (p + 1) * 32;
            bf16* l = sB + ((p + 1) & 1) * (128 * 32) + wid * 32 * 32;
            async16(g, l);
            async16(g + rstep, l + 16 * 32);
        }

        // A fragments straight from global f32
        const float* ga = gA + p * 32;
        float4 va[4][2];
        #pragma unroll
        for (int i = 0; i < 4; ++i) {
            va[i][0] = *(const float4*)(ga + (size_t)i * 16 * 256);
            va[i][1] = *(const float4*)(ga + (size_t)i * 16 * 256 + 4);
        }
        bf16x8 af[4], bfr[4];
        #pragma unroll
        for (int i = 0; i < 4; ++i) af[i] = cvt8(va[i][0], va[i][1]);

        const bf16* sbp = sB + (p & 1) * (128 * 32);
        #pragma unroll
        for (int j = 0; j < 4; ++j)
            bfr[j] = *(const bf16x8*)&sbp[(tn + j * 16 + l15) * 32 + q * 8];

        #pragma unroll
        for (int i = 0; i < 4; ++i)
            #pragma unroll
            for (int j = 0; j < 4; ++j)
                acc[i][j] = __builtin_amdgcn_mfma_f32_16x16x32_bf16(
                    af[i], bfr[j], acc[i][j], 0, 0, 0);
    }

    // C/D layout: col=lane&15, row=q*4+reg (m89/m91-verified)
    #pragma unroll
    for (int j = 0; j < 4; ++j) {
        int col = n0 + tn + j * 16 + l15;
        #pragma unroll
        for (int i = 0; i < 4; ++i) {
            #pragma unroll
            for (int r = 0; r < 4; ++r) {
                int row = m0 + tm + i * 16 + q * 4 + r;
                Cb[(size_t)row * 512 + col] = __float2bfloat16(acc[i][j][r]);
            }
        }
    }
}

// ---------------------------------------------------------------------------
// Fused scan + stage C. Block = (b, 32-t chunk), 2048 blocks, 256 threads.
// Phase 1: scan Bu rows [t0-16, t0+32) (halo 16: |Lam|^16 <= 1.2e-7, exact
//   vs bf16 rounding), 16-deep register prefetch (Bu + starts; starts is
//   wave-uniform -> broadcast load, no LDS). h -> LDS sH (stride 520: 2-way
//   bank aliasing = free). WcT slab 0 pre-issued BEFORE the scan.
// Phase 2: out[t0..t0+32)x256 = sH @ WcT^T + D*x, K=512. WcT slabs async16
//   into double-buffered sB: ONE barrier per K-iter, staging overlaps MFMA.
// LDS: sH 33.3KB + sB 32KB = 65.6KB -> 2 blocks/CU.
// ---------------------------------------------------------------------------
#define SC  32
#define HL  16
#define LDH 520   // sH row stride in elems (1040 B, 16B-aligned)
#define PF  16    // scan prefetch depth (nIter 32/48 both divisible)

__global__ __launch_bounds__(256) void scan_gemmc_kernel(
    const bf16* __restrict__ Bu,     // (M,512)
    const bf16* __restrict__ WcT,    // (256,512)
    const float* __restrict__ lam,   // [2*NH]
    const int* __restrict__ starts,  // (T,B)
    const float* __restrict__ state_re, const float* __restrict__ state_im,
    const float* __restrict__ x,     // (M,256) f32
    const float* __restrict__ Dvec,  // (256,)
    float* __restrict__ out)         // (M,256) f32
{
    __shared__ bf16 sH[SC * LDH];        // 33,280 B
    __shared__ bf16 sB[2 * 256 * 32];    // 32,768 B double-buffered

    const int tid = threadIdx.x;
    const int b   = blockIdx.x & (BATCH - 1);
    const int c   = blockIdx.x / BATCH;
    const int t0  = c * SC;
    const int tstart = (c == 0) ? 0 : t0 - HL;
    const int nIter  = t0 + SC - tstart;      // 32 or 48

    const int lane = tid & 63;
    const int w    = tid >> 6;          // wave -> 64-col group
    const int l15  = lane & 15;
    const int q    = lane >> 4;

    // Pre-issue WcT slab 0 (buf 0): lands during the scan.
    const bf16* gB0 = WcT + (size_t)(w * 64 + (lane >> 2)) * 512 + (lane & 3) * 8;
    {
        bf16* l = sB + w * 64 * 32;
        async16(gB0,            l);
        async16(gB0 + 16 * 512, l + 16 * 32);
        async16(gB0 + 32 * 512, l + 32 * 32);
        async16(gB0 + 48 * 512, l + 48 * 32);
    }

    // ---- Phase 1: scan (thread = complex head) ----
    const int h = tid;
    float lr = lam[h], li = lam[NH + h];
    float hre = 0.0f, him = 0.0f;
    if (c == 0) { hre = state_re[b * NH + h]; him = state_im[b * NH + h]; }

    const bf16* bp = Bu + ((size_t)tstart * BATCH + b) * 512 + 2 * h;
    const int* stp = starts + tstart * BATCH + b;
    const size_t tstride = (size_t)BATCH * 512;   // elems per t step

    unsigned int vbuf[PF];
    int stbuf[PF];
    #pragma unroll
    for (int p = 0; p < PF; ++p) {
        vbuf[p]  = *(const unsigned int*)(bp + (size_t)p * tstride);
        stbuf[p] = stp[p * BATCH];
    }

    const int skip = nIter - SC;   // halo iterations before t0
    for (int base = 0; base < nIter; base += PF) {
        #pragma unroll
        for (int p = 0; p < PF; ++p) {
            int it = base + p;
            unsigned int v = vbuf[p];
            int st = stbuf[p];
            int tp = it + PF;
            if (tp < nIter) {
                vbuf[p]  = *(const unsigned int*)(bp + (size_t)tp * tstride);
                stbuf[p] = stp[tp * BATCH];
            }
            float br = __uint_as_float(v << 16);
            float bi = __uint_as_float(v & 0xffff0000u);
            float nr = st ? br : fmaf(lr, hre, fmaf(-li, him, br));
            float ni = st ? bi : fmaf(lr, him, fmaf(li, hre, bi));
            hre = nr; him = ni;
            int tl = it - skip;
            if (tl >= 0) {
                unsigned int packed =
                    ((unsigned int)f2bf_bits(him) << 16) | f2bf_bits(hre);
                *(unsigned int*)&sH[tl * LDH + 2 * h] = packed;
            }
        }
    }

    // ---- Phase 2: GEMM 32x256, K=512, A from sH, B dbuf async ----
    f32x4 acc[2][4];
    #pragma unroll
    for (int i = 0; i < 2; ++i)
        #pragma unroll
        for (int j = 0; j < 4; ++j) acc[i][j] = (f32x4){0.f, 0.f, 0.f, 0.f};

    for (int p = 0; p < 16; ++p) {
        __syncthreads();   // p=0: sH ready + slab0 drained; else slab p drained
        if (p < 15) {      // issue slab p+1 into other buffer (overlaps MFMA)
            const bf16* g = gB0 + (p + 1) * 32;
            bf16* l = sB + ((p + 1) & 1) * (256 * 32) + w * 64 * 32;
            async16(g,            l);
            async16(g + 16 * 512, l + 16 * 32);
            async16(g + 32 * 512, l + 32 * 32);
            async16(g + 48 * 512, l + 48 * 32);
        }

        const bf16* sbp = sB + (p & 1) * (256 * 32);
        bf16x8 af[2], bfr[4];
        #pragma unroll
        for (int i = 0; i < 2; ++i)
            af[i] = *(const bf16x8*)&sH[(i * 16 + l15) * LDH + p * 32 + q * 8];
        #pragma unroll
        for (int j = 0; j < 4; ++j)
            bfr[j] = *(const bf16x8*)&sbp[(w * 64 + j * 16 + l15) * 32 + q * 8];
        #pragma unroll
        for (int i = 0; i < 2; ++i)
            #pragma unroll
            for (int j = 0; j < 4; ++j)
                acc[i][j] = __builtin_amdgcn_mfma_f32_16x16x32_bf16(
                    af[i], bfr[j], acc[i][j], 0, 0, 0);
    }

    // Epilogue: out rows m = (t0 + tl)*16 + b, + D*x skip
    #pragma unroll
    for (int j = 0; j < 4; ++j) {
        int col = w * 64 + j * 16 + l15;
        float dv = Dvec[col];
        #pragma unroll
        for (int i = 0; i < 2; ++i) {
            #pragma unroll
            for (int r = 0; r < 4; ++r) {
                int tl = i * 16 + q * 4 + r;
                size_t m = (size_t)(t0 + tl) * BATCH + b;
                out[m * 256 + col] = acc[i][j][r] + dv * x[m * 256 + col];
            }
        }
    }
}

// ---------------------------------------------------------------------------
// Launch. Inputs: x, starts, state_re, state_im, nu_log, theta_log,
// B_re, B_im, C_re, C_im, D (f32 except starts -> const int*). Output f32.
// Workspace: lam 2KB | WaT 256KB | WcT 256KB | Bu 64MB (~65MB total).
// ---------------------------------------------------------------------------
extern "C" void kernel_launch(void* const* d_in, const int* in_sizes, int n_in,
                              void* d_out, int out_size, void* d_ws, size_t ws_size,
                              hipStream_t stream)
{
    const float* x         = (const float*)d_in[0];
    const int*   starts    = (const int*)d_in[1];
    const float* state_re  = (const float*)d_in[2];
    const float* state_im  = (const float*)d_in[3];
    const float* nu_log    = (const float*)d_in[4];
    const float* theta_log = (const float*)d_in[5];
    const float* B_re      = (const float*)d_in[6];
    const float* B_im      = (const float*)d_in[7];
    const float* C_re      = (const float*)d_in[8];
    const float* C_im      = (const float*)d_in[9];
    const float* Dvec      = (const float*)d_in[10];
    float* out = (float*)d_out;

    char* ws = (char*)d_ws;
    float* lam = (float*)ws;                            // 2*NH f32
    bf16*  WaT = (bf16*)(ws + 4096);                    // 512x256 bf16
    bf16*  WcT = (bf16*)(ws + 4096 + 512 * 256 * 2);    // 256x512 bf16
    bf16*  Bu  = (bf16*)(ws + (1 << 20));               // 65536x512 bf16 (64MB)

    prep_lam_kernel<<<1, 256, 0, stream>>>(nu_log, theta_log, lam);
    prep_w_kernel<<<1024, 256, 0, stream>>>(nu_log, B_re, B_im, C_re, C_im, WaT, WcT);

    // Stage A: Bu = x @ WaT^T   (M=65536, K=256, N=512). 2048 blocks.
    gemm_a_kernel<<<2048, 256, 0, stream>>>(x, WaT, Bu);

    // Fused scan + stage C: 2048 blocks = (chunk, b).
    scan_gemmc_kernel<<<(T_LEN / SC) * BATCH, 256, 0, stream>>>(
        Bu, WcT, lam, starts, state_re, state_im, x, Dvec, out);
}